// Round 16
// baseline (99.137 us; speedup 1.0000x reference)
//
#include <hip/hip_runtime.h>

#define B 256
#define KDIM 8
#define IDIM 1152
#define CDIM 10
#define CO 160
#define IK 9216        // IDIM*KDIM
#define NPART 6        // split-K partials in k_s (grid 240 <= 256 CUs)
#define AIT 6          // i's per k_agr block (grid 192*4 = 768 = 3/CU exact)

typedef __bf16 bf16x8 __attribute__((ext_vector_type(8)));
typedef unsigned short ushort8 __attribute__((ext_vector_type(8)));
typedef float f32x4 __attribute__((ext_vector_type(4)));

__device__ __forceinline__ unsigned short f2bf(float f) {
  unsigned u = __float_as_uint(f);
  unsigned r = u + 0x7fff + ((u >> 16) & 1);   // RNE
  return (unsigned short)(r >> 16);
}

union U8B8 { ushort8 u; bf16x8 h; };
union U64F2 { unsigned long long u; float f[2]; };

// Agent-scope (LLC-coherent, cache-bypassing) accessors for same-kernel
// cross-block traffic (s_part). No fences needed (R10/R11-validated).
__device__ __forceinline__ void st64_llc(void* p, unsigned long long v) {
  __hip_atomic_store((unsigned long long*)p, v, __ATOMIC_RELAXED,
                     __HIP_MEMORY_SCOPE_AGENT);
}
__device__ __forceinline__ unsigned long long ld64_llc(const void* p) {
  return __hip_atomic_load((unsigned long long*)p, __ATOMIC_RELAXED,
                           __HIP_MEMORY_SCOPE_AGENT);
}

// Fragment-order layouts (lane l = lq*16+lr reads base + l*16B):
//   WqP[c][kc][lq][lr][e]        = bf16(W[i=kc*4+lq][c][o=lr][k=e] / 1152)
//   XbP[bt][kc][lq][lr][e]       = bf16(x[b=bt*16+lr][k=e][i=kc*4+lq])
//   XkP[bx][w][bh][kc][lq][lr][e]= bf16(x[b=bh*64+kc*32+lq*8+e][k=lr&7][i=bx*6+w*2+(lr>>3)])
//   outP[bh][nt][kc][lq][lr][e]  = bf16(out[b=bh*64+kc*32+lq*8+e][co=nt*16+lr])
// s_part layout: [bt4][g][b_local(64)][co(160)] f32.

// ---------------------------------------------------------------------------
// Kernel 1 (prep): role A (0..287): x-tile -> XbP + XkP. role B (288..359):
// W -> WqP (scaled by 1/1152, direct); zero logits + counters.
// ---------------------------------------------------------------------------
__global__ void __launch_bounds__(256) k_prep(const float* __restrict__ x,
                                              const float* __restrict__ W,
                                              unsigned short* __restrict__ XbP,
                                              unsigned short* __restrict__ XkP,
                                              unsigned short* __restrict__ WqP,
                                              float* __restrict__ logits,
                                              int* __restrict__ cnt) {
  const int bid = blockIdx.x;
  const int t = threadIdx.x;
  if (bid < 288) {
    __shared__ float tf[KDIM * 1056];         // tile[k][bb][ii]: k*1056+bb*33+ii
    const int i0 = (bid % 36) * 32;
    const int b0 = (bid / 36) * 32;
    const int tx = t & 31, ty = t >> 5;       // ty 0..7
#pragma unroll
    for (int r = 0; r < 4; ++r) {
      int b = b0 + ty + r * 8;
#pragma unroll
      for (int k = 0; k < 8; ++k)
        tf[k * 1056 + (ty + r * 8) * 33 + tx] =
            x[((size_t)b * KDIM + k) * IDIM + i0 + tx];
    }
    __syncthreads();
    // ---- XbP ----
#pragma unroll
    for (int r = 0; r < 4; ++r) {
      int idx = r * 256 + t;
      int bth = idx >> 9, kc8 = (idx >> 6) & 7, lq = (idx >> 4) & 3, lr = idx & 15;
      ushort8 v;
#pragma unroll
      for (int e = 0; e < 8; ++e)
        v[e] = f2bf(tf[e * 1056 + (bth * 16 + lr) * 33 + kc8 * 4 + lq]);
      int bt = (b0 >> 4) + bth;
      int kc = (i0 >> 2) + kc8;
      *reinterpret_cast<ushort8*>(
          &XbP[(((size_t)bt * 288 + kc) * 64 + lq * 16 + lr) * 8]) = v;
    }
    // ---- XkP ----
    {
      const int bh = b0 >> 6, kc = (b0 >> 5) & 1;
#pragma unroll
      for (int r = 0; r < 4; ++r) {
        int idx = r * 256 + t;
        int il = idx >> 5, k = (idx >> 2) & 7, lql = idx & 3;
        int i = i0 + il;
        int bx = i / 6, r6 = i - bx * 6;
        int w = r6 >> 1, lr = (r6 & 1) * 8 + k;
        ushort8 v;
#pragma unroll
        for (int e = 0; e < 8; ++e)
          v[e] = f2bf(tf[k * 1056 + (lql * 8 + e) * 33 + il]);
        *reinterpret_cast<ushort8*>(
            &XkP[((((size_t)(bx * 3 + w) * 4 + bh) * 2 + kc) * 64 + lql * 16 + lr) * 8]) = v;
      }
    }
  } else {
    const int bz = bid - 288;                  // 0..71
    const int i0 = bz * 16;
    const int ii = t >> 4, lr = t & 15;
    const int i = i0 + ii;
    const int kc = i >> 2, lq = i & 3;
    const float sc = 1.f / (float)IDIM;
#pragma unroll
    for (int c = 0; c < CDIM; ++c) {
      const float* src = &W[(size_t)i * 1280 + c * 128 + lr * 8];
      float4 w0 = *(const float4*)src;
      float4 w1 = *(const float4*)(src + 4);
      ushort8 v;
      v[0] = f2bf(w0.x * sc); v[1] = f2bf(w0.y * sc);
      v[2] = f2bf(w0.z * sc); v[3] = f2bf(w0.w * sc);
      v[4] = f2bf(w1.x * sc); v[5] = f2bf(w1.y * sc);
      v[6] = f2bf(w1.z * sc); v[7] = f2bf(w1.w * sc);
      *reinterpret_cast<ushort8*>(
          &WqP[(((size_t)c * 288 + kc) * 64 + lq * 16 + lr) * 8]) = v;
    }
    if (bz < 45) logits[bz * 256 + t] = 0.f;
    if (bz == 45 && t < 16) cnt[t] = 0;
  }
}

// ---------------------------------------------------------------------------
// Kernel 2 (k_s + fused squash tail): MFMA split-K s-GEMM; each block
// publishes its partial via sc1 stores; the LAST block per bt4 (atomic
// counter == 59) reduces all 6 partials and squashes its 64-b slice.
// MODE 0: it0 (q uniform pre-folded into WqP; zero repack) -> outP
// MODE 1: it1 (softmax; qreg = q*1152) -> outP
// MODE 2: it2 (softmax) -> f32 out
// grid (10 c, 4 bt4, 6 g) = 240 blocks.
// ---------------------------------------------------------------------------
template <int MODE>
__global__ void __launch_bounds__(256) k_s(const float* __restrict__ logits,
                                           const unsigned short* __restrict__ WqP,
                                           const unsigned short* __restrict__ XbP,
                                           float* __restrict__ s_part,
                                           unsigned short* __restrict__ outP,
                                           float* __restrict__ out,
                                           int* __restrict__ cnt) {
  const int c = blockIdx.x, bt4 = blockIdx.y, g = blockIdx.z;
  const int t = threadIdx.x, w = t >> 6, l = t & 63;
  const int lr = l & 15, lq = l >> 4;
  const int s = g * 4 + w;                   // 0..23

  __shared__ __align__(16) unsigned char smem[45064];
  float* red = (float*)(smem) + IDIM + 4;    // cross-wave reduce (after cls/red4)
  int* islast = (int*)(smem + 45056);

  float qreg[12];
  if constexpr (MODE != 0) {
    float* cls = (float*)smem;
    float* red4 = cls + IDIM;
    float m = -1e30f;
    for (int i = t; i < IDIM; i += 256) {
      float v = logits[i * CDIM + c];
      cls[i] = v;
      m = fmaxf(m, v);
    }
#pragma unroll
    for (int off = 32; off; off >>= 1) m = fmaxf(m, __shfl_xor(m, off));
    if ((t & 63) == 0) red4[t >> 6] = m;
    __syncthreads();
    m = fmaxf(fmaxf(red4[0], red4[1]), fmaxf(red4[2], red4[3]));
    __syncthreads();
    float ps = 0.f;
    for (int i = t; i < IDIM; i += 256) {
      float e = expf(cls[i] - m);
      cls[i] = e;
      ps += e;
    }
#pragma unroll
    for (int off = 32; off; off >>= 1) ps += __shfl_xor(ps, off);
    if ((t & 63) == 0) red4[t >> 6] = ps;
    __syncthreads();
    const float rinv = (float)IDIM / (red4[0] + red4[1] + red4[2] + red4[3]);
#pragma unroll
    for (int t9 = 0; t9 < 12; ++t9)
      qreg[t9] = cls[(s * 12 + t9) * 4 + lq] * rinv;   // q * 1152
    __syncthreads();
  }

  // ---- MFMA main loop: 12 chunks, lane-coalesced fragment loads ----
  f32x4 acc[4];
#pragma unroll
  for (int j = 0; j < 4; ++j) acc[j] = (f32x4){0.f, 0.f, 0.f, 0.f};

  const unsigned short* Ap  = &WqP[(size_t)c * 147456 + l * 8];
  const unsigned short* Bp0 = &XbP[(size_t)(bt4 * 4 + 0) * 147456 + l * 8];
  const unsigned short* Bp1 = &XbP[(size_t)(bt4 * 4 + 1) * 147456 + l * 8];
  const unsigned short* Bp2 = &XbP[(size_t)(bt4 * 4 + 2) * 147456 + l * 8];
  const unsigned short* Bp3 = &XbP[(size_t)(bt4 * 4 + 3) * 147456 + l * 8];

#pragma unroll 4
  for (int t9 = 0; t9 < 12; ++t9) {
    const int off = (s * 12 + t9) * 512;
    ushort8 av = *reinterpret_cast<const ushort8*>(Ap + off);
    U8B8 b0; b0.u = *reinterpret_cast<const ushort8*>(Bp0 + off);
    U8B8 b1; b1.u = *reinterpret_cast<const ushort8*>(Bp1 + off);
    U8B8 b2; b2.u = *reinterpret_cast<const ushort8*>(Bp2 + off);
    U8B8 b3; b3.u = *reinterpret_cast<const ushort8*>(Bp3 + off);
    U8B8 a;
    if constexpr (MODE == 0) {
      a.u = av;                              // q folded into WqP — no repack
    } else {
#pragma unroll
      for (int e = 0; e < 8; ++e) {
        float f = __uint_as_float((unsigned)av[e] << 16) * qreg[t9];
        a.u[e] = f2bf(f);
      }
    }
    acc[0] = __builtin_amdgcn_mfma_f32_16x16x32_bf16(a.h, b0.h, acc[0], 0, 0, 0);
    acc[1] = __builtin_amdgcn_mfma_f32_16x16x32_bf16(a.h, b1.h, acc[1], 0, 0, 0);
    acc[2] = __builtin_amdgcn_mfma_f32_16x16x32_bf16(a.h, b2.h, acc[2], 0, 0, 0);
    acc[3] = __builtin_amdgcn_mfma_f32_16x16x32_bf16(a.h, b3.h, acc[3], 0, 0, 0);
  }

  // ---- cross-wave reduce ----
  if (w) {
#pragma unroll
    for (int j = 0; j < 4; ++j)
#pragma unroll
      for (int j2 = 0; j2 < 4; ++j2)
        red[(w - 1) * 1088 + l * 17 + j * 4 + j2] = acc[j][j2];
  }
  __syncthreads();
  if (w == 0) {
#pragma unroll
    for (int r = 0; r < 3; ++r)
#pragma unroll
      for (int j = 0; j < 4; ++j)
#pragma unroll
        for (int j2 = 0; j2 < 4; ++j2)
          acc[j][j2] += red[r * 1088 + l * 17 + j * 4 + j2];
    // publish partial: s_part[bt4][g][b_local][co], sc1 (LLC-coherent)
#pragma unroll
    for (int j = 0; j < 4; ++j) {
      union { f32x4 f; unsigned long long u[2]; } cv;
      cv.f = acc[j];
      float* dp = &s_part[((size_t)(bt4 * 6 + g) * 64 + j * 16 + lr) * CO +
                          c * 16 + lq * 4];
      st64_llc(dp, cv.u[0]);
      st64_llc(dp + 2, cv.u[1]);
    }
  }
  __syncthreads();                           // drains vmcnt: stores at LLC
  if (t == 0) {
    int old = atomicAdd(&cnt[MODE * 4 + bt4], 1);
    *islast = (old == 59);
  }
  __syncthreads();
  if (!*islast) return;

  // ---- squash tail (last block per bt4 only; data complete at LLC) ----
  float* sq = (float*)smem;                  // [64][160]
  float* fo = (float*)(smem + 40960);        // [64][16]
  for (int task = t; task < 64 * 80; task += 256) {
    int bl = task / 80, p = task % 80;
    const float* sp = &s_part[((size_t)(bt4 * 6) * 64 + bl) * CO + p * 2];
    float a0 = 0.f, a1 = 0.f;
#pragma unroll
    for (int gg = 0; gg < 6; ++gg) {
      U64F2 cv2; cv2.u = ld64_llc(sp + (size_t)gg * 64 * CO);
      a0 += cv2.f[0];
      a1 += cv2.f[1];
    }
    sq[bl * 160 + p * 2] = a0;
    sq[bl * 160 + p * 2 + 1] = a1;
  }
  __syncthreads();
  for (int task = t; task < 1024; task += 256) {  // (bl, o)
    int bl = task >> 4, o = task & 15;
    float ns = 0.f;
#pragma unroll
    for (int cc = 0; cc < CDIM; ++cc) {
      float v = sq[bl * 160 + cc * 16 + o];
      ns += v * v;
    }
    fo[bl * 16 + o] = (ns / (1.f + ns)) / (sqrtf(ns) + 1e-10f);
  }
  __syncthreads();
  if constexpr (MODE == 2) {
    for (int task = t; task < 64 * 160; task += 256) {
      int bl = task / 160, co = task % 160;
      out[(size_t)(bt4 * 64 + bl) * CO + co] = sq[bl * 160 + co] * fo[bl * 16 + (co & 15)];
    }
  } else {
    for (int task = t; task < 1280; task += 256) {  // (nt, kc, lq2, lr2)
      int nt = task / 128, r = task % 128;
      int kc = r >> 6, lq2 = (r >> 4) & 3, lr2 = r & 15;
      ushort8 v;
#pragma unroll
      for (int e = 0; e < 8; ++e) {
        int bl = kc * 32 + lq2 * 8 + e;
        v[e] = f2bf(sq[bl * 160 + nt * 16 + lr2] * fo[bl * 16 + lr2]);
      }
      *reinterpret_cast<ushort8*>(
          &outP[((((size_t)bt4 * 10 + nt) * 2 + kc) * 4 + lq2) * 128 + lr2 * 8]) = v;
    }
  }
}

// ---------------------------------------------------------------------------
// Kernel 3 (k_agr): y = x*out^T via MFMA (coalesced XkP/outP), yl transposed
// [co][ik] for float4 W-contract, atomicAdd logits. grid (192,4) = 3/CU.
// ---------------------------------------------------------------------------
__global__ void __launch_bounds__(256) k_agr(const float* __restrict__ W,
                                             const unsigned short* __restrict__ XkP,
                                             const unsigned short* __restrict__ outP,
                                             float* __restrict__ logits) {
  const int bx = blockIdx.x;                 // i0 = bx*6, ik0 = bx*48
  const int bh = blockIdx.y;                 // b0 = bh*64
  const int t = threadIdx.x, w = t >> 6, l = t & 63;
  const int lr = l & 15, lq = l >> 4;
  __shared__ __align__(16) float yl[CO][52];   // [co][ik]

  if (w < 3) {
    f32x4 acc[10];
#pragma unroll
    for (int nt = 0; nt < 10; ++nt) acc[nt] = (f32x4){0.f, 0.f, 0.f, 0.f};
    const unsigned short* Ap = &XkP[(((size_t)(bx * 3 + w) * 4 + bh) * 1024) + l * 8];
    const unsigned short* Bp = &outP[(size_t)bh * 10240 + l * 8];
#pragma unroll
    for (int kc = 0; kc < 2; ++kc) {
      U8B8 a; a.u = *reinterpret_cast<const ushort8*>(Ap + kc * 512);
#pragma unroll
      for (int nt = 0; nt < 10; ++nt) {
        U8B8 bv;
        bv.u = *reinterpret_cast<const ushort8*>(Bp + nt * 1024 + kc * 512);
        acc[nt] = __builtin_amdgcn_mfma_f32_16x16x32_bf16(a.h, bv.h, acc[nt], 0, 0, 0);
      }
    }
#pragma unroll
    for (int nt = 0; nt < 10; ++nt)
#pragma unroll
      for (int j = 0; j < 4; ++j)
        yl[nt * 16 + lr][w * 16 + lq * 4 + j] = acc[nt][j];
  }
  __syncthreads();

  if (t < 120) {                             // 6 i x 10 c x 2 oh
    const int ii = t / 20, rem = t % 20, cc = rem >> 1, oh = rem & 1;
    const float* Wp = &W[((size_t)(bx * AIT + ii) * CDIM + cc) * 128 + oh * 64];
    float sum = 0.f;
#pragma unroll
    for (int o = 0; o < 8; ++o) {
      float4 w0 = *(const float4*)(&Wp[o * 8]);
      float4 w1 = *(const float4*)(&Wp[o * 8 + 4]);
      const float* yr = &yl[cc * 16 + oh * 8 + o][ii * 8];
      float4 y0 = *(const float4*)(&yr[0]);
      float4 y1 = *(const float4*)(&yr[4]);
      sum += w0.x * y0.x + w0.y * y0.y + w0.z * y0.z + w0.w * y0.w
           + w1.x * y1.x + w1.y * y1.y + w1.z * y1.z + w1.w * y1.w;
    }
    sum += __shfl_xor(sum, 1);
    if (oh == 0)
      atomicAdd(&logits[(bx * AIT + ii) * CDIM + cc], sum * (1.f / (float)B));
  }
}

// ---------------------------------------------------------------------------
extern "C" void kernel_launch(void* const* d_in, const int* in_sizes, int n_in,
                              void* d_out, int out_size, void* d_ws, size_t ws_size,
                              hipStream_t stream) {
  const float* x = (const float*)d_in[0];       // [B,K,I] f32
  const float* W = (const float*)d_in[1];       // [I,C,O,K] f32
  float* out = (float*)d_out;                   // [B,C,O,1] f32

  float* logits = (float*)d_ws;                              // I*C f32
  float* s_part = logits + IDIM * CDIM;                      // 4*6*64*160 f32
  unsigned short* XbP = (unsigned short*)(s_part + (size_t)NPART * B * CO);
  unsigned short* XkP = XbP + (size_t)B * IK;                // IK*B
  unsigned short* WqP = XkP + (size_t)IK * B;                // CO*IK
  unsigned short* outP = WqP + (size_t)CO * IK;              // CO*B
  int* cnt = (int*)(outP + (size_t)CO * B);                  // 16 ints

  k_prep<<<360, 256, 0, stream>>>(x, W, XbP, XkP, WqP, logits, cnt);

  dim3 gs(CDIM, 4, NPART);
  k_s<0><<<gs, 256, 0, stream>>>(logits, WqP, XbP, s_part, outP, out, cnt);
  k_agr<<<dim3(IDIM / AIT, 4), 256, 0, stream>>>(W, XkP, outP, logits);
  k_s<1><<<gs, 256, 0, stream>>>(logits, WqP, XbP, s_part, outP, out, cnt);
  k_agr<<<dim3(IDIM / AIT, 4), 256, 0, stream>>>(W, XkP, outP, logits);
  k_s<2><<<gs, 256, 0, stream>>>(logits, WqP, XbP, s_part, outP, out, cnt);
}

// Round 17
// 68.297 us; speedup vs baseline: 1.4516x; 1.4516x over previous
//
#include <hip/hip_runtime.h>

#define B 256
#define KDIM 8
#define IDIM 1152
#define CDIM 10
#define CO 160
#define IK 9216        // IDIM*KDIM
#define NPART 6        // split-K partials in k_s (grid 240 <= 256 CUs)
#define AIT 6          // i's per k_agr block (grid 192*4 = 768 = 3/CU exact)

typedef __bf16 bf16x8 __attribute__((ext_vector_type(8)));
typedef unsigned short ushort8 __attribute__((ext_vector_type(8)));
typedef float f32x4 __attribute__((ext_vector_type(4)));

__device__ __forceinline__ unsigned short f2bf(float f) {
  unsigned u = __float_as_uint(f);
  unsigned r = u + 0x7fff + ((u >> 16) & 1);   // RNE
  return (unsigned short)(r >> 16);
}

union U8B8 { ushort8 u; bf16x8 h; };

// Fragment-order layouts (lane l = lq*16+lr reads base + l*16B, coalesced):
//   WqP[c][kc][lq][lr][e]        = bf16(W[i=kc*4+lq][c][o=lr][k=e] / 1152)
//   XbP[bt][kc][lq][lr][e]       = bf16(x[b=bt*16+lr][k=e][i=kc*4+lq])
//   XkP[bx][w][bh][kc][lq][lr][e]= bf16(x[b=bh*64+kc*32+lq*8+e][k=lr&7][i=bx*6+w*2+(lr>>3)])
//   outP[bh][nt][kc][lq][lr][e]  = bf16(out[b=bh*64+kc*32+lq*8+e][co=nt*16+lr])
// s_part layout: [g][b][co] f32 (cached stores; consumed by k_sqm/k_sqf).

// ---------------------------------------------------------------------------
// Kernel 1 (prep): role A (0..287): x-tile -> XbP + XkP. role B (288..359):
// W -> WqP (scaled by 1/1152, direct); first 45 role-B blocks zero logits.
// ---------------------------------------------------------------------------
__global__ void __launch_bounds__(256) k_prep(const float* __restrict__ x,
                                              const float* __restrict__ W,
                                              unsigned short* __restrict__ XbP,
                                              unsigned short* __restrict__ XkP,
                                              unsigned short* __restrict__ WqP,
                                              float* __restrict__ logits) {
  const int bid = blockIdx.x;
  const int t = threadIdx.x;
  if (bid < 288) {
    __shared__ float tf[KDIM * 1056];         // tile[k][bb][ii]: k*1056+bb*33+ii
    const int i0 = (bid % 36) * 32;
    const int b0 = (bid / 36) * 32;
    const int tx = t & 31, ty = t >> 5;       // ty 0..7
#pragma unroll
    for (int r = 0; r < 4; ++r) {
      int b = b0 + ty + r * 8;
#pragma unroll
      for (int k = 0; k < 8; ++k)
        tf[k * 1056 + (ty + r * 8) * 33 + tx] =
            x[((size_t)b * KDIM + k) * IDIM + i0 + tx];
    }
    __syncthreads();
    // ---- XbP ----
#pragma unroll
    for (int r = 0; r < 4; ++r) {
      int idx = r * 256 + t;
      int bth = idx >> 9, kc8 = (idx >> 6) & 7, lq = (idx >> 4) & 3, lr = idx & 15;
      ushort8 v;
#pragma unroll
      for (int e = 0; e < 8; ++e)
        v[e] = f2bf(tf[e * 1056 + (bth * 16 + lr) * 33 + kc8 * 4 + lq]);
      int bt = (b0 >> 4) + bth;
      int kc = (i0 >> 2) + kc8;
      *reinterpret_cast<ushort8*>(
          &XbP[(((size_t)bt * 288 + kc) * 64 + lq * 16 + lr) * 8]) = v;
    }
    // ---- XkP ----
    {
      const int bh = b0 >> 6, kc = (b0 >> 5) & 1;
#pragma unroll
      for (int r = 0; r < 4; ++r) {
        int idx = r * 256 + t;
        int il = idx >> 5, k = (idx >> 2) & 7, lql = idx & 3;
        int i = i0 + il;
        int bx = i / 6, r6 = i - bx * 6;
        int w = r6 >> 1, lr = (r6 & 1) * 8 + k;
        ushort8 v;
#pragma unroll
        for (int e = 0; e < 8; ++e)
          v[e] = f2bf(tf[k * 1056 + (lql * 8 + e) * 33 + il]);
        *reinterpret_cast<ushort8*>(
            &XkP[((((size_t)(bx * 3 + w) * 4 + bh) * 2 + kc) * 64 + lql * 16 + lr) * 8]) = v;
      }
    }
  } else {
    const int bz = bid - 288;                  // 0..71
    const int i0 = bz * 16;
    const int ii = t >> 4, lr = t & 15;
    const int i = i0 + ii;
    const int kc = i >> 2, lq = i & 3;
    const float sc = 1.f / (float)IDIM;
#pragma unroll
    for (int c = 0; c < CDIM; ++c) {
      const float* src = &W[(size_t)i * 1280 + c * 128 + lr * 8];
      float4 w0 = *(const float4*)src;
      float4 w1 = *(const float4*)(src + 4);
      ushort8 v;
      v[0] = f2bf(w0.x * sc); v[1] = f2bf(w0.y * sc);
      v[2] = f2bf(w0.z * sc); v[3] = f2bf(w0.w * sc);
      v[4] = f2bf(w1.x * sc); v[5] = f2bf(w1.y * sc);
      v[6] = f2bf(w1.z * sc); v[7] = f2bf(w1.w * sc);
      *reinterpret_cast<ushort8*>(
          &WqP[(((size_t)c * 288 + kc) * 64 + lq * 16 + lr) * 8]) = v;
    }
    if (bz < 45) logits[bz * 256 + t] = 0.f;
  }
}

// ---------------------------------------------------------------------------
// Kernel 2 (k_s): MFMA split-K, coalesced fragment loads.
// MODE 0 (it0): q uniform, pre-folded into WqP -> no softmax, no repack.
// MODE 1 (it1/it2): softmax; qreg = q*1152 compensates WqP's 1/1152 scale.
// grid (10 c, 4 bt4, 6 g) = 240 blocks; wave-split s = g*4+w, 12 chunks.
// ---------------------------------------------------------------------------
template <int MODE>
__global__ void __launch_bounds__(256) k_s(const float* __restrict__ logits,
                                           const unsigned short* __restrict__ WqP,
                                           const unsigned short* __restrict__ XbP,
                                           float* __restrict__ s_part) {
  const int c = blockIdx.x, bt4 = blockIdx.y, g = blockIdx.z;
  const int t = threadIdx.x, w = t >> 6, l = t & 63;
  const int lr = l & 15, lq = l >> 4;
  const int s = g * 4 + w;                   // 0..23

  __shared__ float red[3 * 1088];

  float qreg[12];
  if constexpr (MODE != 0) {
    __shared__ float cls[IDIM];
    __shared__ float red4[4];
    float m = -1e30f;
    for (int i = t; i < IDIM; i += 256) {
      float v = logits[i * CDIM + c];
      cls[i] = v;
      m = fmaxf(m, v);
    }
#pragma unroll
    for (int off = 32; off; off >>= 1) m = fmaxf(m, __shfl_xor(m, off));
    if ((t & 63) == 0) red4[t >> 6] = m;
    __syncthreads();
    m = fmaxf(fmaxf(red4[0], red4[1]), fmaxf(red4[2], red4[3]));
    __syncthreads();
    float ps = 0.f;
    for (int i = t; i < IDIM; i += 256) {
      float e = expf(cls[i] - m);
      cls[i] = e;
      ps += e;
    }
#pragma unroll
    for (int off = 32; off; off >>= 1) ps += __shfl_xor(ps, off);
    if ((t & 63) == 0) red4[t >> 6] = ps;
    __syncthreads();
    const float rinv = (float)IDIM / (red4[0] + red4[1] + red4[2] + red4[3]);
#pragma unroll
    for (int t9 = 0; t9 < 12; ++t9)
      qreg[t9] = cls[(s * 12 + t9) * 4 + lq] * rinv;   // q * 1152
  }

  // ---- MFMA main loop: 12 chunks, all loads lane-coalesced ----
  f32x4 acc[4];
#pragma unroll
  for (int j = 0; j < 4; ++j) acc[j] = (f32x4){0.f, 0.f, 0.f, 0.f};

  const unsigned short* Ap  = &WqP[(size_t)c * 147456 + l * 8];
  const unsigned short* Bp0 = &XbP[(size_t)(bt4 * 4 + 0) * 147456 + l * 8];
  const unsigned short* Bp1 = &XbP[(size_t)(bt4 * 4 + 1) * 147456 + l * 8];
  const unsigned short* Bp2 = &XbP[(size_t)(bt4 * 4 + 2) * 147456 + l * 8];
  const unsigned short* Bp3 = &XbP[(size_t)(bt4 * 4 + 3) * 147456 + l * 8];

#pragma unroll 4
  for (int t9 = 0; t9 < 12; ++t9) {
    const int off = (s * 12 + t9) * 512;
    ushort8 av = *reinterpret_cast<const ushort8*>(Ap + off);
    U8B8 b0; b0.u = *reinterpret_cast<const ushort8*>(Bp0 + off);
    U8B8 b1; b1.u = *reinterpret_cast<const ushort8*>(Bp1 + off);
    U8B8 b2; b2.u = *reinterpret_cast<const ushort8*>(Bp2 + off);
    U8B8 b3; b3.u = *reinterpret_cast<const ushort8*>(Bp3 + off);
    U8B8 a;
    if constexpr (MODE == 0) {
      a.u = av;                              // q folded into WqP — no repack
    } else {
#pragma unroll
      for (int e = 0; e < 8; ++e) {
        float f = __uint_as_float((unsigned)av[e] << 16) * qreg[t9];
        a.u[e] = f2bf(f);
      }
    }
    acc[0] = __builtin_amdgcn_mfma_f32_16x16x32_bf16(a.h, b0.h, acc[0], 0, 0, 0);
    acc[1] = __builtin_amdgcn_mfma_f32_16x16x32_bf16(a.h, b1.h, acc[1], 0, 0, 0);
    acc[2] = __builtin_amdgcn_mfma_f32_16x16x32_bf16(a.h, b2.h, acc[2], 0, 0, 0);
    acc[3] = __builtin_amdgcn_mfma_f32_16x16x32_bf16(a.h, b3.h, acc[3], 0, 0, 0);
  }

  // ---- cross-wave reduce, store by wave 0 (cached stores) ----
  if (w) {
#pragma unroll
    for (int j = 0; j < 4; ++j)
#pragma unroll
      for (int j2 = 0; j2 < 4; ++j2)
        red[(w - 1) * 1088 + l * 17 + j * 4 + j2] = acc[j][j2];
  }
  __syncthreads();
  if (w == 0) {
#pragma unroll
    for (int r = 0; r < 3; ++r)
#pragma unroll
      for (int j = 0; j < 4; ++j)
#pragma unroll
        for (int j2 = 0; j2 < 4; ++j2)
          acc[j][j2] += red[r * 1088 + l * 17 + j * 4 + j2];
#pragma unroll
    for (int j = 0; j < 4; ++j)
#pragma unroll
      for (int j2 = 0; j2 < 4; ++j2)
        s_part[((size_t)g * B + bt4 * 64 + j * 16 + lr) * CO + c * 16 + lq * 4 + j2] =
            acc[j][j2];
  }
}

// ---------------------------------------------------------------------------
// Kernel 3 (k_sqm): reduce partials + squash -> outP (fragment order).
// grid 32 blocks x 8 b; coalesced co-major reads.
// ---------------------------------------------------------------------------
__global__ void __launch_bounds__(256) k_sqm(const float* __restrict__ s_part,
                                             unsigned short* __restrict__ outP) {
  const int t = threadIdx.x;
  const int b0 = blockIdx.x * 8;
  __shared__ float sq[8][160];
  __shared__ float fo[8][16];
  float vv[8];
  if (t < CO) {
#pragma unroll
    for (int bi = 0; bi < 8; ++bi) {
      float sv = 0.f;
#pragma unroll
      for (int p = 0; p < NPART; ++p)
        sv += s_part[((size_t)p * B + b0 + bi) * CO + t];
      vv[bi] = sv;
      sq[bi][t] = sv * sv;
    }
  }
  __syncthreads();
  if (t < 128) {
    int bi = t >> 4, o = t & 15;
    float ns = 0.f;
#pragma unroll
    for (int c = 0; c < CDIM; ++c) ns += sq[bi][c * 16 + o];
    fo[bi][o] = (ns / (1.f + ns)) / (sqrtf(ns) + 1e-10f);
  }
  __syncthreads();
  if (t < CO) {
    const int nt = t >> 4, lr = t & 15;
    const int bh = b0 >> 6, kc = (b0 >> 5) & 1, lq = (b0 >> 3) & 3;
    ushort8 v;
#pragma unroll
    for (int bi = 0; bi < 8; ++bi) v[bi] = f2bf(vv[bi] * fo[bi][t & 15]);
    *reinterpret_cast<ushort8*>(
        &outP[((((size_t)bh * 10 + nt) * 2 + kc) * 4 + lq) * 128 + lr * 8]) = v;
  }
}

// ---------------------------------------------------------------------------
// Kernel 4 (k_sqf, last iter): reduce + squash -> d_out f32 [b][c][o].
// ---------------------------------------------------------------------------
__global__ void __launch_bounds__(256) k_sqf(const float* __restrict__ s_part,
                                             float* __restrict__ out) {
  const int t = threadIdx.x;
  const int b0 = blockIdx.x * 8;
  __shared__ float sq[8][160];
  __shared__ float fo[8][16];
  float vv[8];
  if (t < CO) {
#pragma unroll
    for (int bi = 0; bi < 8; ++bi) {
      float sv = 0.f;
#pragma unroll
      for (int p = 0; p < NPART; ++p)
        sv += s_part[((size_t)p * B + b0 + bi) * CO + t];
      vv[bi] = sv;
      sq[bi][t] = sv * sv;
    }
  }
  __syncthreads();
  if (t < 128) {
    int bi = t >> 4, o = t & 15;
    float ns = 0.f;
#pragma unroll
    for (int c = 0; c < CDIM; ++c) ns += sq[bi][c * 16 + o];
    fo[bi][o] = (ns / (1.f + ns)) / (sqrtf(ns) + 1e-10f);
  }
  __syncthreads();
  if (t < CO) {
#pragma unroll
    for (int bi = 0; bi < 8; ++bi)
      out[(size_t)(b0 + bi) * CO + t] = vv[bi] * fo[bi][t & 15];
  }
}

// ---------------------------------------------------------------------------
// Kernel 5 (k_agr): y = x*out^T via MFMA (coalesced XkP/outP), yl transposed
// [co][ik] for float4 W-contract, atomicAdd logits. grid (192,4) = 3/CU.
// ---------------------------------------------------------------------------
__global__ void __launch_bounds__(256) k_agr(const float* __restrict__ W,
                                             const unsigned short* __restrict__ XkP,
                                             const unsigned short* __restrict__ outP,
                                             float* __restrict__ logits) {
  const int bx = blockIdx.x;                 // i0 = bx*6, ik0 = bx*48
  const int bh = blockIdx.y;                 // b0 = bh*64
  const int t = threadIdx.x, w = t >> 6, l = t & 63;
  const int lr = l & 15, lq = l >> 4;
  __shared__ __align__(16) float yl[CO][52];   // [co][ik]

  if (w < 3) {
    f32x4 acc[10];
#pragma unroll
    for (int nt = 0; nt < 10; ++nt) acc[nt] = (f32x4){0.f, 0.f, 0.f, 0.f};
    const unsigned short* Ap = &XkP[(((size_t)(bx * 3 + w) * 4 + bh) * 1024) + l * 8];
    const unsigned short* Bp = &outP[(size_t)bh * 10240 + l * 8];
#pragma unroll
    for (int kc = 0; kc < 2; ++kc) {
      U8B8 a; a.u = *reinterpret_cast<const ushort8*>(Ap + kc * 512);
#pragma unroll
      for (int nt = 0; nt < 10; ++nt) {
        U8B8 bv;
        bv.u = *reinterpret_cast<const ushort8*>(Bp + nt * 1024 + kc * 512);
        acc[nt] = __builtin_amdgcn_mfma_f32_16x16x32_bf16(a.h, bv.h, acc[nt], 0, 0, 0);
      }
    }
#pragma unroll
    for (int nt = 0; nt < 10; ++nt)
#pragma unroll
      for (int j = 0; j < 4; ++j)
        yl[nt * 16 + lr][w * 16 + lq * 4 + j] = acc[nt][j];
  }
  __syncthreads();

  if (t < 120) {                             // 6 i x 10 c x 2 oh
    const int ii = t / 20, rem = t % 20, cc = rem >> 1, oh = rem & 1;
    const float* Wp = &W[((size_t)(bx * AIT + ii) * CDIM + cc) * 128 + oh * 64];
    float sum = 0.f;
#pragma unroll
    for (int o = 0; o < 8; ++o) {
      float4 w0 = *(const float4*)(&Wp[o * 8]);
      float4 w1 = *(const float4*)(&Wp[o * 8 + 4]);
      const float* yr = &yl[cc * 16 + oh * 8 + o][ii * 8];
      float4 y0 = *(const float4*)(&yr[0]);
      float4 y1 = *(const float4*)(&yr[4]);
      sum += w0.x * y0.x + w0.y * y0.y + w0.z * y0.z + w0.w * y0.w
           + w1.x * y1.x + w1.y * y1.y + w1.z * y1.z + w1.w * y1.w;
    }
    sum += __shfl_xor(sum, 1);
    if (oh == 0)
      atomicAdd(&logits[(bx * AIT + ii) * CDIM + cc], sum * (1.f / (float)B));
  }
}

// ---------------------------------------------------------------------------
extern "C" void kernel_launch(void* const* d_in, const int* in_sizes, int n_in,
                              void* d_out, int out_size, void* d_ws, size_t ws_size,
                              hipStream_t stream) {
  const float* x = (const float*)d_in[0];       // [B,K,I] f32
  const float* W = (const float*)d_in[1];       // [I,C,O,K] f32
  float* out = (float*)d_out;                   // [B,C,O,1] f32

  float* logits = (float*)d_ws;                              // I*C f32
  float* s_part = logits + IDIM * CDIM;                      // NPART*B*CO f32
  unsigned short* XbP = (unsigned short*)(s_part + (size_t)NPART * B * CO);
  unsigned short* XkP = XbP + (size_t)B * IK;                // IK*B
  unsigned short* WqP = XkP + (size_t)IK * B;                // CO*IK
  unsigned short* outP = WqP + (size_t)CO * IK;              // CO*B

  k_prep<<<360, 256, 0, stream>>>(x, W, XbP, XkP, WqP, logits);

  dim3 gs(CDIM, 4, NPART);
  k_s<0><<<gs, 256, 0, stream>>>(logits, WqP, XbP, s_part);
  k_sqm<<<32, 256, 0, stream>>>(s_part, outP);
  k_agr<<<dim3(IDIM / AIT, 4), 256, 0, stream>>>(W, XkP, outP, logits);
  k_s<1><<<gs, 256, 0, stream>>>(logits, WqP, XbP, s_part);
  k_sqm<<<32, 256, 0, stream>>>(s_part, outP);
  k_agr<<<dim3(IDIM / AIT, 4), 256, 0, stream>>>(W, XkP, outP, logits);
  k_s<1><<<gs, 256, 0, stream>>>(logits, WqP, XbP, s_part);
  k_sqf<<<32, 256, 0, stream>>>(s_part, out);
}